// Round 3
// baseline (57862.616 us; speedup 1.0000x reference)
//
#include <hip/hip_runtime.h>
#include <hip/hip_bf16.h>

// RateRNN: B=128,T=4096,I=128,H=512; h'=0.8h+0.2relu(Wi x + Wr h + br); y=wo.h+bo
#define B_ 128
#define T_ 4096
#define I_ 128
#define H_ 512

typedef __attribute__((ext_vector_type(8))) short short8;
typedef __attribute__((ext_vector_type(4))) float f32x4;

__device__ __forceinline__ unsigned short f2bf(float f) {
  union { float f; unsigned int u; } v; v.f = f;
  unsigned int r = v.u + 0x7FFFu + ((v.u >> 16) & 1u);  // RNE
  return (unsigned short)(r >> 16);
}

__device__ __forceinline__ short8 cvt8(f32x4 a, f32x4 b) {
  union { short8 s; unsigned short u[8]; } r;
#pragma unroll
  for (int j = 0; j < 4; ++j) { r.u[j] = f2bf(a[j]); r.u[4 + j] = f2bf(b[j]); }
  return r.s;
}

__device__ __forceinline__ void st_u64(unsigned long long* p, unsigned long long v) {
  __hip_atomic_store(p, v, __ATOMIC_RELAXED, __HIP_MEMORY_SCOPE_AGENT);
}
__device__ __forceinline__ unsigned long long ld_u64(const unsigned long long* p) {
  return __hip_atomic_load(p, __ATOMIC_RELAXED, __HIP_MEMORY_SCOPE_AGENT);
}

// ---- workspace layout (bytes) ----
#define WBF_BYTES ((size_t)(H_ * H_ + H_ * I_) * 2)            // 655360
#define CNT_OFF   WBF_BYTES                                    // 16 x u32
#define HX_OFF    (CNT_OFF + 64)                               // 655424 (16B aligned)
#define HX_BYTES  ((size_t)8 * 2 * 16 * H_ * 2)                // 262144
#define YP_OFF    (((HX_OFF + HX_BYTES) + 63) & ~(size_t)63)   // 917568
#define YP_BYTES  ((size_t)8 * T_ * 2 * 16 * 4)                // 4 MB
#define WS_NEED   (YP_OFF + YP_BYTES)

// One-time fp32 -> bf16 conversion of w_rec, w_in; zero the 16 pair counters.
__global__ void cvt_w_kernel(const float* __restrict__ w_rec,
                             const float* __restrict__ w_in,
                             unsigned short* __restrict__ wbf,
                             unsigned int* __restrict__ cnt) {
  int i = blockIdx.x * blockDim.x + threadIdx.x;
  if (i < H_ * H_) wbf[i] = f2bf(w_rec[i]);
  if (i < H_ * I_) wbf[H_ * H_ + i] = f2bf(w_in[i]);
  if (cnt != nullptr && i < 16) cnt[i] = 0;
}

// ---------------------------------------------------------------------------
// 16 blocks x 512 threads (8 waves, LB(512,2) -> 256 VGPR cap, 1 block/CU).
// pair = blockIdx&7 owns batch rows pair*16..+15; half = blockIdx>>3 owns cols
// half*256..+255; wave owns 32 cols. w_rec slice PINNED in 128 VGPRs (asm);
// w_in slice in LDS. Own-half h via LDS (parity dbuf); partner half via L3
// using RELAXED agent atomics only (sc1 path, no wbl2/inv fences):
//   publish: relaxed atomic stores -> s_waitcnt vmcnt(0) -> relaxed cnt add
//   consume: relaxed poll of partner cnt -> relaxed sc1 loads
// Operand-swapped MFMA 16x16x32 bf16: A=W (m=g), B=h^T/x^T (n=batch),
// C row=q*4+r (g), col=lane&15 (batch).
// ---------------------------------------------------------------------------
__global__ __launch_bounds__(512, 2)
void rnn_pair_kernel(const float* __restrict__ inputs,
                     const float* __restrict__ hidden,
                     const float* __restrict__ b_rec,
                     const float* __restrict__ w_out,
                     const unsigned short* __restrict__ wbf,
                     unsigned short* __restrict__ hx,
                     unsigned int* __restrict__ cnt,
                     float* __restrict__ yp,
                     float* __restrict__ hfin) {
  __shared__ alignas(16) unsigned short wi_s[256 * 138];   // 69 KB, stride 138 (bank-safe)
  __shared__ alignas(16) unsigned short h_s[2][16 * 266];  // 17 KB, stride 266
  __shared__ float yps[2][8][16];

  const int tid  = threadIdx.x;
  const int wave = tid >> 6;
  const int lane = tid & 63;
  const int q    = lane >> 4;
  const int c    = lane & 15;
  const int pair = blockIdx.x & 7;
  const int half = blockIdx.x >> 3;
  const int r0   = pair * 16;
  const int colw = wave * 32;            // wave col base within half
  const int n0   = half * 256 + colw;    // global col base

  // ---- LDS fills: w_in slice + h(0) own half (slot 0) ----
  for (int e = tid; e < 256 * 128; e += 512) {
    int col = e >> 7, k = e & 127;
    wi_s[col * 138 + k] = wbf[(size_t)H_ * H_ + (size_t)(half * 256 + col) * I_ + k];
  }
  for (int e = tid; e < 16 * 256; e += 512) {
    int r = e >> 8, col = e & 255;
    h_s[0][r * 266 + col] = f2bf(hidden[(size_t)(r0 + r) * H_ + half * 256 + col]);
  }

  // ---- w_rec slice -> pinned registers: wr[global kstep 0..15][nt 0..1] ----
  f32x4 wr[16][2];
#pragma unroll
  for (int kk = 0; kk < 16; ++kk)
#pragma unroll
    for (int nt = 0; nt < 2; ++nt) {
      wr[kk][nt] = *(const f32x4*)(wbf + (size_t)(n0 + nt * 16 + c) * H_ + kk * 32 + q * 8);
      asm volatile("" : "+v"(wr[kk][nt]));  // opaque: no remat, stays in VGPRs
    }

  // Persistent fp32 state, C-layout: hreg[nt][r] = h[b=r0+c][g=n0+nt*16+q*4+r]
  f32x4 hreg[2], brec[2], wout[2];
#pragma unroll
  for (int nt = 0; nt < 2; ++nt)
#pragma unroll
    for (int r = 0; r < 4; ++r) {
      const int g = n0 + nt * 16 + q * 4 + r;
      hreg[nt][r] = hidden[(size_t)(r0 + c) * H_ + g];
      brec[nt][r] = b_rec[g];
      wout[nt][r] = w_out[g];
    }

  unsigned int* mycnt = cnt + (pair * 2 + half);
  unsigned int* ocnt  = cnt + (pair * 2 + (1 - half));
  unsigned short* hxp = hx + (size_t)pair * 2 * 16 * H_;  // [slot][16][512]

  const float* xbase = inputs + (size_t)(r0 + c) * T_ * I_ + q * 8;

  // x(0) prefetch + convert
  f32x4 xa[4], xb[4];
#pragma unroll
  for (int kk = 0; kk < 4; ++kk) {
    xa[kk] = *(const f32x4*)(xbase + kk * 32);
    xb[kk] = *(const f32x4*)(xbase + kk * 32 + 4);
  }
  short8 xc[4];
#pragma unroll
  for (int kk = 0; kk < 4; ++kk) xc[kk] = cvt8(xa[kk], xb[kk]);

  // publish h(0) -> L3 slot 0, then counter
#pragma unroll
  for (int nt = 0; nt < 2; ++nt) {
    union { unsigned short u[4]; unsigned long long q8; } pk;
#pragma unroll
    for (int r = 0; r < 4; ++r) pk.u[r] = f2bf(hreg[nt][r]);
    st_u64((unsigned long long*)(hxp + (size_t)c * H_ + n0 + nt * 16 + q * 4), pk.q8);
  }
  asm volatile("s_waitcnt vmcnt(0)" ::: "memory");
  if (lane == 0)
    __hip_atomic_fetch_add(mycnt, 1u, __ATOMIC_RELAXED, __HIP_MEMORY_SCOPE_AGENT);

  for (int t = 0; t < T_; ++t) {
    const int rs = t & 1, wsl = rs ^ 1;
    __syncthreads();

    // wave 0 drains y(t-1) from LDS partials (written last iter, slot wsl)
    if (wave == 0 && lane < 16 && t > 0) {
      float s = 0.f;
#pragma unroll
      for (int w = 0; w < 8; ++w) s += yps[wsl][w][lane];
      yp[(((size_t)pair * T_ + (t - 1)) * 2 + half) * 16 + lane] = s;
    }

    f32x4 acc[2];
    acc[0] = (f32x4){0.f, 0.f, 0.f, 0.f};
    acc[1] = (f32x4){0.f, 0.f, 0.f, 0.f};

    // input projection: A = w_in (LDS), B = x^T
#pragma unroll
    for (int kk = 0; kk < 4; ++kk)
#pragma unroll
      for (int nt = 0; nt < 2; ++nt) {
        short8 a = *(const short8*)(&wi_s[(colw + nt * 16 + c) * 138 + kk * 32 + q * 8]);
        acc[nt] = __builtin_amdgcn_mfma_f32_16x16x32_bf16(a, xc[kk], acc[nt], 0, 0, 0);
      }

    // wait for partner h(t)
    const unsigned target = 8u * (unsigned)(t + 1);
    while (__hip_atomic_load(ocnt, __ATOMIC_RELAXED, __HIP_MEMORY_SCOPE_AGENT) < target) {}
    asm volatile("" ::: "memory");

    const unsigned short* hxr =
        hxp + ((size_t)rs * 16 + c) * H_ + (1 - half) * 256 + q * 8;

    // partner chunk A (ksteps 0..3 of partner half) - hide L3 latency under own MFMAs
    unsigned long long pqa[4][2];
#pragma unroll
    for (int kp = 0; kp < 4; ++kp) {
      const unsigned long long* pp = (const unsigned long long*)(hxr + kp * 32);
      pqa[kp][0] = ld_u64(pp); pqa[kp][1] = ld_u64(pp + 1);
    }
    // x(t+1) prefetch
    {
      const float* xp = xbase + (size_t)((t + 1 < T_) ? t + 1 : t) * I_;
#pragma unroll
      for (int kk = 0; kk < 4; ++kk) {
        xa[kk] = *(const f32x4*)(xp + kk * 32);
        xb[kk] = *(const f32x4*)(xp + kk * 32 + 4);
      }
    }

    // own-half recurrent MFMAs (B from LDS)
#pragma unroll
    for (int kl = 0; kl < 8; ++kl) {
      short8 b = *(const short8*)(&h_s[rs][c * 266 + kl * 32 + q * 8]);
      const int kg = half * 8 + kl;
#pragma unroll
      for (int nt = 0; nt < 2; ++nt)
        acc[nt] = __builtin_amdgcn_mfma_f32_16x16x32_bf16(
            __builtin_bit_cast(short8, wr[kg][nt]), b, acc[nt], 0, 0, 0);
    }

    // partner chunk B loads
    unsigned long long pqb[4][2];
#pragma unroll
    for (int kp = 0; kp < 4; ++kp) {
      const unsigned long long* pp = (const unsigned long long*)(hxr + (kp + 4) * 32);
      pqb[kp][0] = ld_u64(pp); pqb[kp][1] = ld_u64(pp + 1);
    }

    // partner recurrent MFMAs
#pragma unroll
    for (int kp = 0; kp < 8; ++kp) {
      union { unsigned long long q8[2]; short8 s; } u;
      u.q8[0] = (kp < 4) ? pqa[kp][0] : pqb[kp - 4][0];
      u.q8[1] = (kp < 4) ? pqa[kp][1] : pqb[kp - 4][1];
      const int kg = (1 - half) * 8 + kp;
#pragma unroll
      for (int nt = 0; nt < 2; ++nt)
        acc[nt] = __builtin_amdgcn_mfma_f32_16x16x32_bf16(
            __builtin_bit_cast(short8, wr[kg][nt]), u.s, acc[nt], 0, 0, 0);
    }

    // epilogue: relu + leaky update, publish h(t+1) (LDS + L3), y partial
    float yl = 0.f;
    unsigned short* hxw = hxp + ((size_t)wsl * 16 + c) * H_;
#pragma unroll
    for (int nt = 0; nt < 2; ++nt) {
      union { unsigned short u[4]; unsigned long long q8; } pk;
#pragma unroll
      for (int r = 0; r < 4; ++r) {
        float act = fmaxf(acc[nt][r] + brec[nt][r], 0.f);
        float h = hreg[nt][r] * 0.8f + 0.2f * act;
        hreg[nt][r] = h;
        pk.u[r] = f2bf(h);
        yl = __builtin_fmaf(wout[nt][r], h, yl);
      }
      *(unsigned long long*)(&h_s[wsl][c * 266 + colw + nt * 16 + q * 4]) = pk.q8;
      if (t + 1 < T_)
        st_u64((unsigned long long*)(hxw + n0 + nt * 16 + q * 4), pk.q8);
    }
    yl += __shfl_xor(yl, 16, 64);
    yl += __shfl_xor(yl, 32, 64);
    if (lane < 16) yps[rs][wave][lane] = yl;

    // convert x(t+1) for next iter
#pragma unroll
    for (int kk = 0; kk < 4; ++kk) xc[kk] = cvt8(xa[kk], xb[kk]);

    if (t + 1 < T_) {
      asm volatile("s_waitcnt vmcnt(0)" ::: "memory");
      if (lane == 0)
        __hip_atomic_fetch_add(mycnt, 1u, __ATOMIC_RELAXED, __HIP_MEMORY_SCOPE_AGENT);
    }
  }

  __syncthreads();
  if (wave == 0 && lane < 16) {
    float s = 0.f;
#pragma unroll
    for (int w = 0; w < 8; ++w) s += yps[(T_ - 1) & 1][w][lane];
    yp[(((size_t)pair * T_ + (T_ - 1)) * 2 + half) * 16 + lane] = s;
  }

  // h_final (fp32 master state, coalesced dwordx4)
#pragma unroll
  for (int nt = 0; nt < 2; ++nt)
    *(f32x4*)(hfin + (size_t)(r0 + c) * H_ + n0 + nt * 16 + q * 4) = hreg[nt];
}

// out[b][t] = b_out + yp[pair][t][0][b%16] + yp[pair][t][1][b%16]
__global__ void reduce_y_kernel(const float* __restrict__ yp,
                                const float* __restrict__ b_out,
                                float* __restrict__ out) {
  const int idx = blockIdx.x * 256 + threadIdx.x;  // B*T
  const int t = idx & (T_ - 1);
  const int b = idx >> 12;
  const int pair = b >> 4, bi = b & 15;
  const size_t base = ((size_t)pair * T_ + t) * 2 * 16;
  out[(size_t)b * T_ + t] = b_out[0] + yp[base + bi] + yp[base + 16 + bi];
}

// ---------------------------------------------------------------------------
// Fallback (round-1 kernel) for small workspace.
// ---------------------------------------------------------------------------
template <bool WBF16>
__global__ __launch_bounds__(512, 2)
void rnn_kernel_fb(const float* __restrict__ inputs,
                   const float* __restrict__ hidden,
                   const float* __restrict__ w_in_f,
                   const float* __restrict__ w_rec_f,
                   const float* __restrict__ b_rec,
                   const float* __restrict__ w_out,
                   const float* __restrict__ b_out,
                   const unsigned short* __restrict__ wbf,
                   float* __restrict__ out) {
  __shared__ alignas(16) unsigned short hs[2][16][520];
  __shared__ alignas(16) float ypart[2][8][16];

  const int tid  = threadIdx.x;
  const int wave = tid >> 6;
  const int lane = tid & 63;
  const int q    = lane >> 4;
  const int c    = lane & 15;
  const int r0   = blockIdx.x * 16;
  const int n0   = wave * 64;

  for (int e = tid; e < 16 * H_; e += 512) {
    int rr = e >> 9, cc = e & (H_ - 1);
    hs[0][rr][cc] = f2bf(hidden[(size_t)(r0 + rr) * H_ + cc]);
  }

  f32x4 hreg[4];
  float brec[4], wout[4];
#pragma unroll
  for (int nt = 0; nt < 4; ++nt) {
    const int col = n0 + nt * 16 + c;
    brec[nt] = b_rec[col];
    wout[nt] = w_out[col];
#pragma unroll
    for (int r = 0; r < 4; ++r)
      hreg[nt][r] = hidden[(size_t)(r0 + q * 4 + r) * H_ + col];
  }
  const float bout = b_out[0];
  __syncthreads();

  const unsigned short* wrecb = wbf;
  const unsigned short* winb  = wbf + H_ * H_;
  const size_t wr_off = (size_t)(n0 + c) * H_ + q * 8;
  const size_t wi_off = (size_t)(n0 + c) * I_ + q * 8;
  const float* xbase = inputs + (size_t)(r0 + c) * T_ * I_ + q * 8;

#pragma unroll 2
  for (int t = 0; t < T_; ++t) {
    const int rb = t & 1, wb = rb ^ 1;
    f32x4 xf[4][2];
    const float* xp = xbase + (size_t)t * I_;
#pragma unroll
    for (int kk = 0; kk < 4; ++kk) {
      xf[kk][0] = *(const f32x4*)(xp + kk * 32);
      xf[kk][1] = *(const f32x4*)(xp + kk * 32 + 4);
    }
    f32x4 acc[4];
#pragma unroll
    for (int nt = 0; nt < 4; ++nt) acc[nt] = (f32x4){0.f, 0.f, 0.f, 0.f};
    const unsigned short* hrow = &hs[rb][c][q * 8];
#pragma unroll
    for (int kk = 0; kk < 16; ++kk) {
      short8 a = *(const short8*)(hrow + kk * 32);
#pragma unroll
      for (int nt = 0; nt < 4; ++nt) {
        short8 b;
        if constexpr (WBF16) {
          b = *(const short8*)(wrecb + wr_off + (size_t)nt * 16 * H_ + kk * 32);
        } else {
          const float* p = w_rec_f + wr_off + (size_t)nt * 16 * H_ + kk * 32;
          b = cvt8(*(const f32x4*)p, *(const f32x4*)(p + 4));
        }
        acc[nt] = __builtin_amdgcn_mfma_f32_16x16x32_bf16(a, b, acc[nt], 0, 0, 0);
      }
    }
#pragma unroll
    for (int kk = 0; kk < 4; ++kk) {
      short8 ax = cvt8(xf[kk][0], xf[kk][1]);
#pragma unroll
      for (int nt = 0; nt < 4; ++nt) {
        short8 b;
        if constexpr (WBF16) {
          b = *(const short8*)(winb + wi_off + (size_t)nt * 16 * I_ + kk * 32);
        } else {
          const float* p = w_in_f + wi_off + (size_t)nt * 16 * I_ + kk * 32;
          b = cvt8(*(const f32x4*)p, *(const f32x4*)(p + 4));
        }
        acc[nt] = __builtin_amdgcn_mfma_f32_16x16x32_bf16(ax, b, acc[nt], 0, 0, 0);
      }
    }
    float yp2[4] = {0.f, 0.f, 0.f, 0.f};
#pragma unroll
    for (int nt = 0; nt < 4; ++nt) {
#pragma unroll
      for (int r = 0; r < 4; ++r) {
        float act = fmaxf(acc[nt][r] + brec[nt], 0.f);
        float h = hreg[nt][r] * 0.8f + 0.2f * act;
        hreg[nt][r] = h;
        hs[wb][q * 4 + r][n0 + nt * 16 + c] = f2bf(h);
        yp2[r] = __builtin_fmaf(wout[nt], h, yp2[r]);
      }
    }
#pragma unroll
    for (int off = 8; off >= 1; off >>= 1) {
#pragma unroll
      for (int r = 0; r < 4; ++r) yp2[r] += __shfl_xor(yp2[r], off, 64);
    }
    if (c == 0)
      *(f32x4*)&ypart[wb][wave][q * 4] = (f32x4){yp2[0], yp2[1], yp2[2], yp2[3]};
    __syncthreads();
    if (tid < 16) {
      float s = bout;
#pragma unroll
      for (int w = 0; w < 8; ++w) s += ypart[wb][w][tid];
      out[(size_t)(r0 + tid) * T_ + t] = s;
    }
  }
  float* hfin = out + (size_t)B_ * T_;
#pragma unroll
  for (int nt = 0; nt < 4; ++nt)
#pragma unroll
    for (int r = 0; r < 4; ++r)
      hfin[(size_t)(r0 + q * 4 + r) * H_ + n0 + nt * 16 + c] = hreg[nt][r];
}

extern "C" void kernel_launch(void* const* d_in, const int* in_sizes, int n_in,
                              void* d_out, int out_size, void* d_ws, size_t ws_size,
                              hipStream_t stream) {
  const float* inputs = (const float*)d_in[0];
  const float* hidden = (const float*)d_in[1];
  const float* w_in   = (const float*)d_in[2];
  const float* w_rec  = (const float*)d_in[3];
  const float* b_rec  = (const float*)d_in[4];
  const float* w_out  = (const float*)d_in[5];
  const float* b_out  = (const float*)d_in[6];
  float* out = (float*)d_out;

  if (ws_size >= WS_NEED) {
    unsigned short* wbf = (unsigned short*)d_ws;
    unsigned int*   cnt = (unsigned int*)((char*)d_ws + CNT_OFF);
    unsigned short* hx  = (unsigned short*)((char*)d_ws + HX_OFF);
    float*          yp  = (float*)((char*)d_ws + YP_OFF);
    float*          hfin = out + (size_t)B_ * T_;
    cvt_w_kernel<<<dim3(1024), dim3(256), 0, stream>>>(w_rec, w_in, wbf, cnt);
    rnn_pair_kernel<<<dim3(16), dim3(512), 0, stream>>>(
        inputs, hidden, b_rec, w_out, wbf, hx, cnt, yp, hfin);
    reduce_y_kernel<<<dim3((B_ * T_) / 256), dim3(256), 0, stream>>>(yp, b_out, out);
  } else if (ws_size >= WBF_BYTES) {
    unsigned short* wbf = (unsigned short*)d_ws;
    cvt_w_kernel<<<dim3(1024), dim3(256), 0, stream>>>(w_rec, w_in, wbf, nullptr);
    rnn_kernel_fb<true><<<dim3(8), dim3(512), 0, stream>>>(
        inputs, hidden, w_in, w_rec, b_rec, w_out, b_out, wbf, out);
  } else {
    rnn_kernel_fb<false><<<dim3(8), dim3(512), 0, stream>>>(
        inputs, hidden, w_in, w_rec, b_rec, w_out, b_out, (const unsigned short*)nullptr, out);
  }
}